// Round 3
// baseline (129.949 us; speedup 1.0000x reference)
//
#include <hip/hip_runtime.h>
#include <math.h>

#define NB 24
#define DM 128
#define NH 8
#define DK 16
#define LL 512
#define HB (NH * NB)   // 192

// ---------------------------------------------------------------------------
// Workspace layout (BYTES):
//   xThi/xTlo [NB][LL][DM] ushort : x transposed, split bf16 (B-frag layout)
//   headT     [NB][LL][DM]        : attention out, bf16, B-frag layout for Wo
// (W split is done in-kernel from fp32; qb/kb/vb live in LDS.)
// ---------------------------------------------------------------------------
#define XTH_OFF 0
#define XTL_OFF 3145728
#define HT_OFF  6291456

typedef __attribute__((ext_vector_type(8))) short bf16x8;   // 4 VGPR MFMA A/B
typedef __attribute__((ext_vector_type(4))) float f32x4;    // MFMA C/D
typedef __attribute__((ext_vector_type(4))) int   i32x4;

#define MFMA  __builtin_amdgcn_mfma_f32_16x16x32_bf16
#define EXP2  __builtin_amdgcn_exp2f
#define BPERM __builtin_amdgcn_ds_bpermute

// bf16 rounding (round-half-up), result kept in the high half of a uint
static __device__ __forceinline__ unsigned bfr(float x) {
    return (__float_as_uint(x) + 0x8000u) & 0xffff0000u;
}

// packed bf16 pair via HW cvt: lo16 = bf16(a), hi16 = bf16(b)  (RNE)
static __device__ __forceinline__ unsigned cvtpk(float a, float b) {
    unsigned r;
    asm("v_cvt_pk_bf16_f32 %0, %1, %2" : "=v"(r) : "v"(a), "v"(b));
    return r;
}

// split 8 consecutive fp32 into hi/lo bf16x8 A-fragments (same bfr math as
// the old prep W-split: bit-identical results)
static __device__ __forceinline__ void wsplit(const float* __restrict__ p,
                                              bf16x8& aH, bf16x8& aL) {
    const float4 f0 = *(const float4*)p;
    const float4 f1 = *(const float4*)(p + 4);
    const float f[8] = {f0.x, f0.y, f0.z, f0.w, f1.x, f1.y, f1.z, f1.w};
    i32x4 h, l;
    #pragma unroll
    for (int q = 0; q < 4; ++q) {
        const unsigned h0 = bfr(f[2 * q]), h1 = bfr(f[2 * q + 1]);
        const unsigned e0 = bfr(f[2 * q]     - __uint_as_float(h0));
        const unsigned e1 = bfr(f[2 * q + 1] - __uint_as_float(h1));
        h[q] = (int)((h0 >> 16) | (h1 & 0xffff0000u));
        l[q] = (int)((e0 >> 16) | (e1 & 0xffff0000u));
    }
    aH = __builtin_bit_cast(bf16x8, h);
    aL = __builtin_bit_cast(bf16x8, l);
}

// ---------------------------------------------------------------------------
// Kernel 0: prep. 192 blocks: x -> xThi/xTlo (LDS transpose, two 64-row
// halves, 16.6 KB LDS). W split now happens inside qkv_attn.
// ---------------------------------------------------------------------------
__global__ __launch_bounds__(256)
void prep(const float* __restrict__ x,
          unsigned short* __restrict__ xthi,
          unsigned short* __restrict__ xtlo)
{
    __shared__ float T[64][65];                       // 16.6 KB
    const int bid = blockIdx.x, tid = threadIdx.x;
    const int b = bid >> 3, lc = bid & 7;

    #pragma unroll
    for (int half = 0; half < 2; ++half) {
        const int d0 = half << 6;
        const float* __restrict__ xb =
            x + (size_t)b * 65536 + (size_t)d0 * LL + lc * 64;
        if (half) __syncthreads();                    // T reuse fence
        #pragma unroll
        for (int i = 0; i < 16; ++i) {                // coalesced 64-float runs
            const int idx = i * 256 + tid;
            T[idx >> 6][idx & 63] = xb[(size_t)(idx >> 6) * LL + (idx & 63)];
        }
        __syncthreads();
        #pragma unroll
        for (int i = 0; i < 8; ++i) {                 // 2 elems/lane, packed
            const int idx = (i * 256 + tid) * 2;
            const int l = idx >> 6, dd = idx & 63;
            const float v0 = T[dd][l], v1 = T[dd + 1][l];
            const unsigned h0 = bfr(v0), h1 = bfr(v1);
            const unsigned e0 = bfr(v0 - __uint_as_float(h0));
            const unsigned e1 = bfr(v1 - __uint_as_float(h1));
            const size_t o = (size_t)b * 65536 +
                             (size_t)(lc * 64 + l) * DM + d0 + dd;
            *(unsigned*)(xthi + o) = (h0 >> 16) | (h1 & 0xffff0000u);
            *(unsigned*)(xtlo + o) = (e0 >> 16) | (e1 & 0xffff0000u);
        }
    }
}

// ---------------------------------------------------------------------------
// Fused QKV + attention. 384 blocks = (hb, mhalf) x 512 threads (8 waves).
// Block handles m in [mhalf*256, mhalf*256+256).
// Phase 1: wave wv computes Q,V for l in [wv*64, wv*64+64) and K for
//   m in [mhalf*256+wv*32, +32) -- same MFMA structure as the validated qkv
//   kernel, W split from fp32 in-register. LDS layouts unchanged (padded
//   strides 40 / 520 ushorts, phase-2 reads minimum-aliasing).
//   LDS = 40 (Q) + 20 (K half) + 16.25 (V) = 76.25 KB -> 2 blocks/CU.
// Phase 2: wave wv runs the validated online-softmax attention for its own
//   32 m (one sub-tile: half the serial chain of the previous version).
// ---------------------------------------------------------------------------
static __device__ __forceinline__ void soft_pv(
    const f32x4& s0, const f32x4& s1, float tm, float& bar, float& sm,
    f32x4& O, const bf16x8& aV, int aLo, int aHi, bool up)
{
    const float nb = fmaxf(bar, tm + 32.f);
    const float f  = EXP2(bar - nb);
    bar = nb;
    const float e0 = EXP2(s0[0] - nb), e1 = EXP2(s0[1] - nb);
    const float e2 = EXP2(s0[2] - nb), e3 = EXP2(s0[3] - nb);
    const float e4 = EXP2(s1[0] - nb), e5 = EXP2(s1[1] - nb);
    const float e6 = EXP2(s1[2] - nb), e7 = EXP2(s1[3] - nb);
    const float sacc = ((e0 + e1) + (e2 + e3)) + ((e4 + e5) + (e6 + e7));
    sm = fmaf(sm, f, sacc);
    O *= f;
    const unsigned c0 = cvtpk(e0, e1), c1 = cvtpk(e2, e3);
    const unsigned c2 = cvtpk(e4, e5), c3 = cvtpk(e6, e7);
    const int p00 = BPERM(aLo, (int)c0), p02 = BPERM(aLo, (int)c2);
    const int p10 = BPERM(aLo, (int)c1), p12 = BPERM(aLo, (int)c3);
    const int p20 = BPERM(aHi, (int)c0), p22 = BPERM(aHi, (int)c2);
    const int p30 = BPERM(aHi, (int)c1), p32 = BPERM(aHi, (int)c3);
    i32x4 bi = { up ? p00 : p02, up ? p10 : p12,
                 up ? p20 : p22, up ? p30 : p32 };
    O = MFMA(aV, __builtin_bit_cast(bf16x8, bi), O, 0, 0, 0);
}

#define QK_STRIDE 40     // ushorts per row (32 data + 8 pad)
#define V_STRIDE  520    // ushorts per row (512 data + 8 pad)
#define KROWS     256    // K rows per block (m-half)

__global__ __launch_bounds__(512, 4)
void qkv_attn(const unsigned short* __restrict__ xthi,
              const unsigned short* __restrict__ xtlo,
              const float* __restrict__ Wq,
              const float* __restrict__ Wk,
              const float* __restrict__ Wv,
              unsigned short* __restrict__ ht)
{
    __shared__ unsigned short qs[LL * QK_STRIDE];     // 40 KB
    __shared__ unsigned short ks[KROWS * QK_STRIDE];  // 20 KB
    __shared__ unsigned short vs[DK * V_STRIDE];      // 16.25 KB

    const int hb    = blockIdx.x >> 1;
    const int mhalf = blockIdx.x & 1;
    const int b     = hb % NB;
    const int wv    = threadIdx.x >> 6;               // 0..7
    const int lane  = threadIdx.x & 63;
    const int g     = lane >> 4;
    const int mR    = lane & 15;
    const int lQ    = wv * 64;                        // Q/V l-base
    const int kloc  = wv * 32;                        // K local row base

    // ---------------- Phase 1: QKV projection into LDS ----------------
    {
        const float* __restrict__ wqp = Wq + (size_t)hb * 2048 + mR * 128 + g * 8;
        const float* __restrict__ wkp = Wk + (size_t)hb * 2048 + mR * 128 + g * 8;
        const float* __restrict__ wvp = Wv + (size_t)hb * 2048 + mR * 128 + g * 8;
        const unsigned short* __restrict__ xh = xthi + (size_t)b * 65536 + g * 8;
        const unsigned short* __restrict__ xl = xtlo + (size_t)b * 65536 + g * 8;

        f32x4 CQ[4], CV[4], CK[2];
        #pragma unroll
        for (int t = 0; t < 4; ++t) {
            CQ[t] = (f32x4){0.f, 0.f, 0.f, 0.f};
            CV[t] = (f32x4){0.f, 0.f, 0.f, 0.f};
        }
        CK[0] = (f32x4){0.f, 0.f, 0.f, 0.f};
        CK[1] = (f32x4){0.f, 0.f, 0.f, 0.f};

        #pragma unroll
        for (int kk = 0; kk < 4; ++kk) {
            bf16x8 aH, aL;
            // --- K (2 tiles at m-rows mhalf*256 + kloc + t*16 + mR) ---
            {
                bf16x8 kH[2], kL[2];
                #pragma unroll
                for (int t = 0; t < 2; ++t) {
                    const size_t ro =
                        (size_t)(mhalf * 256 + kloc + t * 16 + mR) * DM + kk * 32;
                    kH[t] = *(const bf16x8*)(xh + ro);
                    kL[t] = *(const bf16x8*)(xl + ro);
                }
                wsplit(wkp + kk * 32, aH, aL);
                #pragma unroll
                for (int t = 0; t < 2; ++t) {
                    CK[t] = MFMA(aH, kH[t], CK[t], 0, 0, 0);
                    CK[t] = MFMA(aH, kL[t], CK[t], 0, 0, 0);
                    CK[t] = MFMA(aL, kH[t], CK[t], 0, 0, 0);
                }
            }
            // --- Q and V share x rows lQ + t*16 + mR ---
            bf16x8 bH[4], bL[4];
            #pragma unroll
            for (int t = 0; t < 4; ++t) {
                const size_t ro = (size_t)(lQ + t * 16 + mR) * DM + kk * 32;
                bH[t] = *(const bf16x8*)(xh + ro);
                bL[t] = *(const bf16x8*)(xl + ro);
            }
            wsplit(wqp + kk * 32, aH, aL);
            #pragma unroll
            for (int t = 0; t < 4; ++t) {
                CQ[t] = MFMA(aH, bH[t], CQ[t], 0, 0, 0);
                CQ[t] = MFMA(aH, bL[t], CQ[t], 0, 0, 0);
                CQ[t] = MFMA(aL, bH[t], CQ[t], 0, 0, 0);
            }
            wsplit(wvp + kk * 32, aH, aL);
            #pragma unroll
            for (int t = 0; t < 4; ++t) {
                CV[t] = MFMA(aH, bH[t], CV[t], 0, 0, 0);
                CV[t] = MFMA(aH, bL[t], CV[t], 0, 0, 0);
                CV[t] = MFMA(aL, bH[t], CV[t], 0, 0, 0);
            }
        }

        // V -> vs[v][l] (plain bf16, padded stride)
        #pragma unroll
        for (int t = 0; t < 4; ++t) {
            const int l = lQ + t * 16 + mR;
            #pragma unroll
            for (int i = 0; i < 4; ++i)
                vs[(4 * g + i) * V_STRIDE + l] =
                    (unsigned short)(bfr(CV[t][i]) >> 16);
        }
        // Q -> split rows [hi(16)|lo(16)], padded stride
        #pragma unroll
        for (int t = 0; t < 4; ++t) {
            const int l = lQ + t * 16 + mR;
            ushort4 hi4, lo4;
            #pragma unroll
            for (int i = 0; i < 4; ++i) {
                const float v = CQ[t][i];
                const unsigned h = bfr(v);
                const unsigned lw = bfr(v - __uint_as_float(h));
                ((unsigned short*)&hi4)[i] = (unsigned short)(h >> 16);
                ((unsigned short*)&lo4)[i] = (unsigned short)(lw >> 16);
            }
            *(ushort4*)(qs + l * QK_STRIDE + 4 * g)      = hi4;
            *(ushort4*)(qs + l * QK_STRIDE + 16 + 4 * g) = lo4;
        }
        // K -> split rows, pre-scaled by 0.25*log2e, local rows
        #pragma unroll
        for (int t = 0; t < 2; ++t) {
            const int r = kloc + t * 16 + mR;
            ushort4 hi4, lo4;
            #pragma unroll
            for (int i = 0; i < 4; ++i) {
                const float v = CK[t][i] * (0.25f * 1.44269504f);
                const unsigned h = bfr(v);
                const unsigned lw = bfr(v - __uint_as_float(h));
                ((unsigned short*)&hi4)[i] = (unsigned short)(h >> 16);
                ((unsigned short*)&lo4)[i] = (unsigned short)(lw >> 16);
            }
            *(ushort4*)(ks + r * QK_STRIDE + 4 * g)      = hi4;
            *(ushort4*)(ks + r * QK_STRIDE + 16 + 4 * g) = lo4;
        }
    }

    __syncthreads();

    // ---------------- Phase 2: flash attention from LDS ----------------
    const unsigned short* Kr0 = ks + (kloc + mR) * QK_STRIDE;
    const unsigned short* Kr1 = Kr0 + 16 * QK_STRIDE;
    const bf16x8 K0  = *(const bf16x8*)(Kr0 + g * 8);
    const bf16x8 K0s = *(const bf16x8*)(Kr0 + (g ^ 2) * 8);
    const bf16x8 K1  = *(const bf16x8*)(Kr1 + g * 8);
    const bf16x8 K1s = *(const bf16x8*)(Kr1 + (g ^ 2) * 8);

    const unsigned short* qrow = qs + mR * QK_STRIDE + g * 8;
    const unsigned short* vrow = vs + mR * V_STRIDE + g * 8;

    f32x4 O0 = {0.f,0.f,0.f,0.f}, O1 = {0.f,0.f,0.f,0.f};
    float bar0 = -1e30f, bar1 = -1e30f, sm0 = 0.f, sm1 = 0.f;

    const int aLo = ((g & 1) * 32 + mR) * 4;
    const int aHi = aLo + 64;
    const bool up = (g < 2);

    for (int l = 0; l < LL; l += 32) {
        const bf16x8 aQ0 = *(const bf16x8*)(qrow + l * QK_STRIDE);
        const bf16x8 aQ1 = *(const bf16x8*)(qrow + (l + 16) * QK_STRIDE);
        const bf16x8 aV  = *(const bf16x8*)(vrow + l);

        const f32x4 z = {0.f,0.f,0.f,0.f};
        f32x4 sA0 = MFMA(aQ0, K0, z, 0,0,0);   sA0 = MFMA(aQ0, K0s, sA0, 0,0,0);
        f32x4 sB0 = MFMA(aQ0, K1, z, 0,0,0);   sB0 = MFMA(aQ0, K1s, sB0, 0,0,0);
        f32x4 sA1 = MFMA(aQ1, K0, z, 0,0,0);   sA1 = MFMA(aQ1, K0s, sA1, 0,0,0);
        f32x4 sB1 = MFMA(aQ1, K1, z, 0,0,0);   sB1 = MFMA(aQ1, K1s, sB1, 0,0,0);

        float tmA = fmaxf(fmaxf(fmaxf(sA0[0],sA0[1]), fmaxf(sA0[2],sA0[3])),
                          fmaxf(fmaxf(sA1[0],sA1[1]), fmaxf(sA1[2],sA1[3])));
        float tmB = fmaxf(fmaxf(fmaxf(sB0[0],sB0[1]), fmaxf(sB0[2],sB0[3])),
                          fmaxf(fmaxf(sB1[0],sB1[1]), fmaxf(sB1[2],sB1[3])));
        tmA = fmaxf(tmA, __shfl_xor(tmA, 16, 64));
        tmA = fmaxf(tmA, __shfl_xor(tmA, 32, 64));
        tmB = fmaxf(tmB, __shfl_xor(tmB, 16, 64));
        tmB = fmaxf(tmB, __shfl_xor(tmB, 32, 64));

        const bool pA = __any(tmA + 64.f > bar0);
        const bool pB = __any(tmB + 64.f > bar1);
        if (pA) soft_pv(sA0, sA1, tmA, bar0, sm0, O0, aV, aLo, aHi, up);
        if (pB) soft_pv(sB0, sB1, tmB, bar1, sm1, O1, aV, aLo, aHi, up);
    }

    sm0 += __shfl_xor(sm0, 16, 64);  sm0 += __shfl_xor(sm0, 32, 64);
    sm1 += __shfl_xor(sm1, 16, 64);  sm1 += __shfl_xor(sm1, 32, 64);
    const float i0 = 1.f / sm0, i1 = 1.f / sm1;

    const int h = hb / NB, bb = hb % NB;
    const int mb = mhalf * 256 + kloc;
    unsigned short* __restrict__ ho =
        ht + (size_t)bb * 65536 + (size_t)(mb + mR) * DM + h * 16 + 4 * g;
    ushort4 p0, p1;
    #pragma unroll
    for (int i = 0; i < 4; ++i) {
        ((unsigned short*)&p0)[i] = (unsigned short)(bfr(O0[i] * i0) >> 16);
        ((unsigned short*)&p1)[i] = (unsigned short)(bfr(O1[i] * i1) >> 16);
    }
    *(ushort4*)ho             = p0;
    *(ushort4*)(ho + 16 * DM) = p1;
}

// ---------------------------------------------------------------------------
// Kernel 3: out = Wo @ headT on MFMA. 768 blocks = (b, mq 2, nq 16) x 4 waves.
// Wo read as fp32, converted to bf16 A-frags in-kernel.
// ---------------------------------------------------------------------------
__global__ __launch_bounds__(256)
void out_mfma(const float* __restrict__ Wo,
              const unsigned short* __restrict__ ht,
              float* __restrict__ out)
{
    const int blk  = blockIdx.x;
    const int b    = blk >> 5;
    const int mq   = (blk >> 4) & 1;
    const int nq   = blk & 15;
    const int wv   = threadIdx.x >> 6;
    const int lane = threadIdx.x & 63;
    const int g = lane >> 4, mR = lane & 15;
    const int m0 = (mq * 4 + wv) * 16;
    const int n0 = nq * 32;

    const float* __restrict__ A =
        Wo + (size_t)b * 16384 + (size_t)(m0 + mR) * DM + g * 8;
    const unsigned short* __restrict__ B = ht + (size_t)b * 65536 + g * 8;

    f32x4 C0 = {0.f,0.f,0.f,0.f}, C1 = {0.f,0.f,0.f,0.f};
    #pragma unroll
    for (int kk = 0; kk < 4; ++kk) {
        const float4 f0 = *(const float4*)(A + kk * 32);
        const float4 f1 = *(const float4*)(A + kk * 32 + 4);
        i32x4 w;
        w[0] = (int)cvtpk(f0.x, f0.y);
        w[1] = (int)cvtpk(f0.z, f0.w);
        w[2] = (int)cvtpk(f1.x, f1.y);
        w[3] = (int)cvtpk(f1.z, f1.w);
        const bf16x8 aW = __builtin_bit_cast(bf16x8, w);
        const bf16x8 b0 = *(const bf16x8*)(B + (size_t)(n0 + mR) * DM + kk * 32);
        const bf16x8 b1 = *(const bf16x8*)(B + (size_t)(n0 + 16 + mR) * DM + kk * 32);
        C0 = MFMA(aW, b0, C0, 0, 0, 0);
        C1 = MFMA(aW, b1, C1, 0, 0, 0);
    }

    float* __restrict__ ob = out + (size_t)b * 65536 + (size_t)(m0 + 4 * g) * LL;
    #pragma unroll
    for (int i = 0; i < 4; ++i) {
        ob[(size_t)i * LL + n0 + mR]      = C0[i];
        ob[(size_t)i * LL + n0 + 16 + mR] = C1[i];
    }
}

extern "C" void kernel_launch(void* const* d_in, const int* in_sizes, int n_in,
                              void* d_out, int out_size, void* d_ws, size_t ws_size,
                              hipStream_t stream) {
    const float* x  = (const float*)d_in[0];
    const float* Wq = (const float*)d_in[1];
    const float* Wk = (const float*)d_in[2];
    const float* Wv = (const float*)d_in[3];
    const float* Wo = (const float*)d_in[4];
    float* out = (float*)d_out;

    char* ws = (char*)d_ws;
    unsigned short* xthi = (unsigned short*)(ws + XTH_OFF);
    unsigned short* xtlo = (unsigned short*)(ws + XTL_OFF);
    unsigned short* ht   = (unsigned short*)(ws + HT_OFF);

    prep     <<<192,     256, 0, stream>>>(x, xthi, xtlo);
    qkv_attn <<<HB * 2,  512, 0, stream>>>(xthi, xtlo, Wq, Wk, Wv, ht);
    out_mfma <<<NB * 32, 256, 0, stream>>>(Wo, ht, out);
}

// Round 4
// 116.963 us; speedup vs baseline: 1.1110x; 1.1110x over previous
//
#include <hip/hip_runtime.h>
#include <math.h>

#define NB 24
#define DM 128
#define NH 8
#define DK 16
#define LL 512
#define HB (NH * NB)   // 192

// ---------------------------------------------------------------------------
// Workspace layout (BYTES):
//   xThi/xTlo [NB][LL][DM] ushort : x transposed, split bf16 (B-frag layout)
//   headT     [NB][LL][DM]        : attention out, bf16, B-frag layout for Wo
// (W split is done in-kernel from fp32; qb/kb/vb live in LDS.)
// ---------------------------------------------------------------------------
#define XTH_OFF 0
#define XTL_OFF 3145728
#define HT_OFF  6291456

typedef __attribute__((ext_vector_type(8))) short bf16x8;   // 4 VGPR MFMA A/B
typedef __attribute__((ext_vector_type(4))) float f32x4;    // MFMA C/D
typedef __attribute__((ext_vector_type(4))) int   i32x4;

#define MFMA  __builtin_amdgcn_mfma_f32_16x16x32_bf16
#define EXP2  __builtin_amdgcn_exp2f
#define BPERM __builtin_amdgcn_ds_bpermute

// bf16 rounding (round-half-up), result kept in the high half of a uint
static __device__ __forceinline__ unsigned bfr(float x) {
    return (__float_as_uint(x) + 0x8000u) & 0xffff0000u;
}

// packed bf16 pair via HW cvt: lo16 = bf16(a), hi16 = bf16(b)  (RNE)
static __device__ __forceinline__ unsigned cvtpk(float a, float b) {
    unsigned r;
    asm("v_cvt_pk_bf16_f32 %0, %1, %2" : "=v"(r) : "v"(a), "v"(b));
    return r;
}

// split 8 consecutive fp32 into hi/lo bf16x8 A-fragments (same bfr math as
// the original prep W-split: bit-identical results)
static __device__ __forceinline__ void wsplit(const float* __restrict__ p,
                                              bf16x8& aH, bf16x8& aL) {
    const float4 f0 = *(const float4*)p;
    const float4 f1 = *(const float4*)(p + 4);
    const float f[8] = {f0.x, f0.y, f0.z, f0.w, f1.x, f1.y, f1.z, f1.w};
    i32x4 h, l;
    #pragma unroll
    for (int q = 0; q < 4; ++q) {
        const unsigned h0 = bfr(f[2 * q]), h1 = bfr(f[2 * q + 1]);
        const unsigned e0 = bfr(f[2 * q]     - __uint_as_float(h0));
        const unsigned e1 = bfr(f[2 * q + 1] - __uint_as_float(h1));
        h[q] = (int)((h0 >> 16) | (h1 & 0xffff0000u));
        l[q] = (int)((e0 >> 16) | (e1 & 0xffff0000u));
    }
    aH = __builtin_bit_cast(bf16x8, h);
    aL = __builtin_bit_cast(bf16x8, l);
}

// ---------------------------------------------------------------------------
// Kernel 0: prep. 192 blocks: x -> xThi/xTlo (LDS transpose, two 64-row
// halves, 16.6 KB LDS).
// ---------------------------------------------------------------------------
__global__ __launch_bounds__(256)
void prep(const float* __restrict__ x,
          unsigned short* __restrict__ xthi,
          unsigned short* __restrict__ xtlo)
{
    __shared__ float T[64][65];                       // 16.6 KB
    const int bid = blockIdx.x, tid = threadIdx.x;
    const int b = bid >> 3, lc = bid & 7;

    #pragma unroll
    for (int half = 0; half < 2; ++half) {
        const int d0 = half << 6;
        const float* __restrict__ xb =
            x + (size_t)b * 65536 + (size_t)d0 * LL + lc * 64;
        if (half) __syncthreads();                    // T reuse fence
        #pragma unroll
        for (int i = 0; i < 16; ++i) {                // coalesced 64-float runs
            const int idx = i * 256 + tid;
            T[idx >> 6][idx & 63] = xb[(size_t)(idx >> 6) * LL + (idx & 63)];
        }
        __syncthreads();
        #pragma unroll
        for (int i = 0; i < 8; ++i) {                 // 2 elems/lane, packed
            const int idx = (i * 256 + tid) * 2;
            const int l = idx >> 6, dd = idx & 63;
            const float v0 = T[dd][l], v1 = T[dd + 1][l];
            const unsigned h0 = bfr(v0), h1 = bfr(v1);
            const unsigned e0 = bfr(v0 - __uint_as_float(h0));
            const unsigned e1 = bfr(v1 - __uint_as_float(h1));
            const size_t o = (size_t)b * 65536 +
                             (size_t)(lc * 64 + l) * DM + d0 + dd;
            *(unsigned*)(xthi + o) = (h0 >> 16) | (h1 & 0xffff0000u);
            *(unsigned*)(xtlo + o) = (e0 >> 16) | (e1 & 0xffff0000u);
        }
    }
}

// ---------------------------------------------------------------------------
// Fused QKV + attention. 192 blocks (one per hb) x 1024 threads (16 waves).
// Phase 1: wave wv computes Q, K, V for l in [wv*32, wv*32+32) -- Q/K/V
//   share the same x B-fragments (loaded once per kk), W split from fp32
//   in-register. LDS layouts are the validated ones (padded strides 40/520).
//   LDS = 40 (Q) + 40 (K) + 16.25 (V) = 96.25 KB -> 1 block/CU, but now
//   16 waves = 4 waves/SIMD (was 2) for latency hiding.
// Phase 2: wave wv runs the validated online-softmax attention for its own
//   32 m (one sub-tile; exact round-3 code path).
// ---------------------------------------------------------------------------
static __device__ __forceinline__ void soft_pv(
    const f32x4& s0, const f32x4& s1, float tm, float& bar, float& sm,
    f32x4& O, const bf16x8& aV, int aLo, int aHi, bool up)
{
    const float nb = fmaxf(bar, tm + 32.f);
    const float f  = EXP2(bar - nb);
    bar = nb;
    const float e0 = EXP2(s0[0] - nb), e1 = EXP2(s0[1] - nb);
    const float e2 = EXP2(s0[2] - nb), e3 = EXP2(s0[3] - nb);
    const float e4 = EXP2(s1[0] - nb), e5 = EXP2(s1[1] - nb);
    const float e6 = EXP2(s1[2] - nb), e7 = EXP2(s1[3] - nb);
    const float sacc = ((e0 + e1) + (e2 + e3)) + ((e4 + e5) + (e6 + e7));
    sm = fmaf(sm, f, sacc);
    O *= f;
    const unsigned c0 = cvtpk(e0, e1), c1 = cvtpk(e2, e3);
    const unsigned c2 = cvtpk(e4, e5), c3 = cvtpk(e6, e7);
    const int p00 = BPERM(aLo, (int)c0), p02 = BPERM(aLo, (int)c2);
    const int p10 = BPERM(aLo, (int)c1), p12 = BPERM(aLo, (int)c3);
    const int p20 = BPERM(aHi, (int)c0), p22 = BPERM(aHi, (int)c2);
    const int p30 = BPERM(aHi, (int)c1), p32 = BPERM(aHi, (int)c3);
    i32x4 bi = { up ? p00 : p02, up ? p10 : p12,
                 up ? p20 : p22, up ? p30 : p32 };
    O = MFMA(aV, __builtin_bit_cast(bf16x8, bi), O, 0, 0, 0);
}

#define QK_STRIDE 40     // ushorts per row (32 data + 8 pad)
#define V_STRIDE  520    // ushorts per row (512 data + 8 pad)

__global__ __launch_bounds__(1024)
void qkv_attn(const unsigned short* __restrict__ xthi,
              const unsigned short* __restrict__ xtlo,
              const float* __restrict__ Wq,
              const float* __restrict__ Wk,
              const float* __restrict__ Wv,
              unsigned short* __restrict__ ht)
{
    __shared__ unsigned short qs[LL * QK_STRIDE];     // 40 KB
    __shared__ unsigned short ks[LL * QK_STRIDE];     // 40 KB
    __shared__ unsigned short vs[DK * V_STRIDE];      // 16.25 KB

    const int hb    = blockIdx.x;
    const int b     = hb % NB;
    const int wv    = threadIdx.x >> 6;               // 0..15
    const int lane  = threadIdx.x & 63;
    const int g     = lane >> 4;
    const int mR    = lane & 15;
    const int lQ    = wv * 32;                        // this wave's l-rows

    // ---------------- Phase 1: QKV projection into LDS ----------------
    {
        const float* __restrict__ wqp = Wq + (size_t)hb * 2048 + mR * 128 + g * 8;
        const float* __restrict__ wkp = Wk + (size_t)hb * 2048 + mR * 128 + g * 8;
        const float* __restrict__ wvp = Wv + (size_t)hb * 2048 + mR * 128 + g * 8;
        const unsigned short* __restrict__ xh = xthi + (size_t)b * 65536 + g * 8;
        const unsigned short* __restrict__ xl = xtlo + (size_t)b * 65536 + g * 8;

        f32x4 CQ[2], CK[2], CV[2];
        #pragma unroll
        for (int t = 0; t < 2; ++t) {
            CQ[t] = (f32x4){0.f, 0.f, 0.f, 0.f};
            CK[t] = (f32x4){0.f, 0.f, 0.f, 0.f};
            CV[t] = (f32x4){0.f, 0.f, 0.f, 0.f};
        }

        #pragma unroll
        for (int kk = 0; kk < 4; ++kk) {
            bf16x8 bH[2], bL[2];
            #pragma unroll
            for (int t = 0; t < 2; ++t) {
                const size_t ro = (size_t)(lQ + t * 16 + mR) * DM + kk * 32;
                bH[t] = *(const bf16x8*)(xh + ro);
                bL[t] = *(const bf16x8*)(xl + ro);
            }
            bf16x8 aH, aL;
            wsplit(wqp + kk * 32, aH, aL);
            #pragma unroll
            for (int t = 0; t < 2; ++t) {
                CQ[t] = MFMA(aH, bH[t], CQ[t], 0, 0, 0);
                CQ[t] = MFMA(aH, bL[t], CQ[t], 0, 0, 0);
                CQ[t] = MFMA(aL, bH[t], CQ[t], 0, 0, 0);
            }
            wsplit(wkp + kk * 32, aH, aL);
            #pragma unroll
            for (int t = 0; t < 2; ++t) {
                CK[t] = MFMA(aH, bH[t], CK[t], 0, 0, 0);
                CK[t] = MFMA(aH, bL[t], CK[t], 0, 0, 0);
                CK[t] = MFMA(aL, bH[t], CK[t], 0, 0, 0);
            }
            wsplit(wvp + kk * 32, aH, aL);
            #pragma unroll
            for (int t = 0; t < 2; ++t) {
                CV[t] = MFMA(aH, bH[t], CV[t], 0, 0, 0);
                CV[t] = MFMA(aH, bL[t], CV[t], 0, 0, 0);
                CV[t] = MFMA(aL, bH[t], CV[t], 0, 0, 0);
            }
        }

        // V -> vs[v][l] (plain bf16, padded stride)
        #pragma unroll
        for (int t = 0; t < 2; ++t) {
            const int l = lQ + t * 16 + mR;
            #pragma unroll
            for (int i = 0; i < 4; ++i)
                vs[(4 * g + i) * V_STRIDE + l] =
                    (unsigned short)(bfr(CV[t][i]) >> 16);
        }
        // Q -> split rows [hi(16)|lo(16)], padded stride
        #pragma unroll
        for (int t = 0; t < 2; ++t) {
            const int l = lQ + t * 16 + mR;
            ushort4 hi4, lo4;
            #pragma unroll
            for (int i = 0; i < 4; ++i) {
                const float v = CQ[t][i];
                const unsigned h = bfr(v);
                const unsigned lw = bfr(v - __uint_as_float(h));
                ((unsigned short*)&hi4)[i] = (unsigned short)(h >> 16);
                ((unsigned short*)&lo4)[i] = (unsigned short)(lw >> 16);
            }
            *(ushort4*)(qs + l * QK_STRIDE + 4 * g)      = hi4;
            *(ushort4*)(qs + l * QK_STRIDE + 16 + 4 * g) = lo4;
        }
        // K -> split rows, pre-scaled by 0.25*log2e
        #pragma unroll
        for (int t = 0; t < 2; ++t) {
            const int r = lQ + t * 16 + mR;
            ushort4 hi4, lo4;
            #pragma unroll
            for (int i = 0; i < 4; ++i) {
                const float v = CK[t][i] * (0.25f * 1.44269504f);
                const unsigned h = bfr(v);
                const unsigned lw = bfr(v - __uint_as_float(h));
                ((unsigned short*)&hi4)[i] = (unsigned short)(h >> 16);
                ((unsigned short*)&lo4)[i] = (unsigned short)(lw >> 16);
            }
            *(ushort4*)(ks + r * QK_STRIDE + 4 * g)      = hi4;
            *(ushort4*)(ks + r * QK_STRIDE + 16 + 4 * g) = lo4;
        }
    }

    __syncthreads();

    // ---------------- Phase 2: flash attention from LDS ----------------
    const int kloc = wv * 32;                         // this wave's m-block
    const unsigned short* Kr0 = ks + (kloc + mR) * QK_STRIDE;
    const unsigned short* Kr1 = Kr0 + 16 * QK_STRIDE;
    const bf16x8 K0  = *(const bf16x8*)(Kr0 + g * 8);
    const bf16x8 K0s = *(const bf16x8*)(Kr0 + (g ^ 2) * 8);
    const bf16x8 K1  = *(const bf16x8*)(Kr1 + g * 8);
    const bf16x8 K1s = *(const bf16x8*)(Kr1 + (g ^ 2) * 8);

    const unsigned short* qrow = qs + mR * QK_STRIDE + g * 8;
    const unsigned short* vrow = vs + mR * V_STRIDE + g * 8;

    f32x4 O0 = {0.f,0.f,0.f,0.f}, O1 = {0.f,0.f,0.f,0.f};
    float bar0 = -1e30f, bar1 = -1e30f, sm0 = 0.f, sm1 = 0.f;

    const int aLo = ((g & 1) * 32 + mR) * 4;
    const int aHi = aLo + 64;
    const bool up = (g < 2);

    for (int l = 0; l < LL; l += 32) {
        const bf16x8 aQ0 = *(const bf16x8*)(qrow + l * QK_STRIDE);
        const bf16x8 aQ1 = *(const bf16x8*)(qrow + (l + 16) * QK_STRIDE);
        const bf16x8 aV  = *(const bf16x8*)(vrow + l);

        const f32x4 z = {0.f,0.f,0.f,0.f};
        f32x4 sA0 = MFMA(aQ0, K0, z, 0,0,0);   sA0 = MFMA(aQ0, K0s, sA0, 0,0,0);
        f32x4 sB0 = MFMA(aQ0, K1, z, 0,0,0);   sB0 = MFMA(aQ0, K1s, sB0, 0,0,0);
        f32x4 sA1 = MFMA(aQ1, K0, z, 0,0,0);   sA1 = MFMA(aQ1, K0s, sA1, 0,0,0);
        f32x4 sB1 = MFMA(aQ1, K1, z, 0,0,0);   sB1 = MFMA(aQ1, K1s, sB1, 0,0,0);

        float tmA = fmaxf(fmaxf(fmaxf(sA0[0],sA0[1]), fmaxf(sA0[2],sA0[3])),
                          fmaxf(fmaxf(sA1[0],sA1[1]), fmaxf(sA1[2],sA1[3])));
        float tmB = fmaxf(fmaxf(fmaxf(sB0[0],sB0[1]), fmaxf(sB0[2],sB0[3])),
                          fmaxf(fmaxf(sB1[0],sB1[1]), fmaxf(sB1[2],sB1[3])));
        tmA = fmaxf(tmA, __shfl_xor(tmA, 16, 64));
        tmA = fmaxf(tmA, __shfl_xor(tmA, 32, 64));
        tmB = fmaxf(tmB, __shfl_xor(tmB, 16, 64));
        tmB = fmaxf(tmB, __shfl_xor(tmB, 32, 64));

        const bool pA = __any(tmA + 64.f > bar0);
        const bool pB = __any(tmB + 64.f > bar1);
        if (pA) soft_pv(sA0, sA1, tmA, bar0, sm0, O0, aV, aLo, aHi, up);
        if (pB) soft_pv(sB0, sB1, tmB, bar1, sm1, O1, aV, aLo, aHi, up);
    }

    sm0 += __shfl_xor(sm0, 16, 64);  sm0 += __shfl_xor(sm0, 32, 64);
    sm1 += __shfl_xor(sm1, 16, 64);  sm1 += __shfl_xor(sm1, 32, 64);
    const float i0 = 1.f / sm0, i1 = 1.f / sm1;

    const int h = hb / NB, bb = hb % NB;
    unsigned short* __restrict__ ho =
        ht + (size_t)bb * 65536 + (size_t)(kloc + mR) * DM + h * 16 + 4 * g;
    ushort4 p0, p1;
    #pragma unroll
    for (int i = 0; i < 4; ++i) {
        ((unsigned short*)&p0)[i] = (unsigned short)(bfr(O0[i] * i0) >> 16);
        ((unsigned short*)&p1)[i] = (unsigned short)(bfr(O1[i] * i1) >> 16);
    }
    *(ushort4*)ho             = p0;
    *(ushort4*)(ho + 16 * DM) = p1;
}

// ---------------------------------------------------------------------------
// Kernel 3: out = Wo @ headT on MFMA. 768 blocks = (b, mq 2, nq 16) x 4 waves.
// Wo read as fp32, converted to bf16 A-frags in-kernel.
// ---------------------------------------------------------------------------
__global__ __launch_bounds__(256)
void out_mfma(const float* __restrict__ Wo,
              const unsigned short* __restrict__ ht,
              float* __restrict__ out)
{
    const int blk  = blockIdx.x;
    const int b    = blk >> 5;
    const int mq   = (blk >> 4) & 1;
    const int nq   = blk & 15;
    const int wv   = threadIdx.x >> 6;
    const int lane = threadIdx.x & 63;
    const int g = lane >> 4, mR = lane & 15;
    const int m0 = (mq * 4 + wv) * 16;
    const int n0 = nq * 32;

    const float* __restrict__ A =
        Wo + (size_t)b * 16384 + (size_t)(m0 + mR) * DM + g * 8;
    const unsigned short* __restrict__ B = ht + (size_t)b * 65536 + g * 8;

    f32x4 C0 = {0.f,0.f,0.f,0.f}, C1 = {0.f,0.f,0.f,0.f};
    #pragma unroll
    for (int kk = 0; kk < 4; ++kk) {
        const float4 f0 = *(const float4*)(A + kk * 32);
        const float4 f1 = *(const float4*)(A + kk * 32 + 4);
        i32x4 w;
        w[0] = (int)cvtpk(f0.x, f0.y);
        w[1] = (int)cvtpk(f0.z, f0.w);
        w[2] = (int)cvtpk(f1.x, f1.y);
        w[3] = (int)cvtpk(f1.z, f1.w);
        const bf16x8 aW = __builtin_bit_cast(bf16x8, w);
        const bf16x8 b0 = *(const bf16x8*)(B + (size_t)(n0 + mR) * DM + kk * 32);
        const bf16x8 b1 = *(const bf16x8*)(B + (size_t)(n0 + 16 + mR) * DM + kk * 32);
        C0 = MFMA(aW, b0, C0, 0, 0, 0);
        C1 = MFMA(aW, b1, C1, 0, 0, 0);
    }

    float* __restrict__ ob = out + (size_t)b * 65536 + (size_t)(m0 + 4 * g) * LL;
    #pragma unroll
    for (int i = 0; i < 4; ++i) {
        ob[(size_t)i * LL + n0 + mR]      = C0[i];
        ob[(size_t)i * LL + n0 + 16 + mR] = C1[i];
    }
}

extern "C" void kernel_launch(void* const* d_in, const int* in_sizes, int n_in,
                              void* d_out, int out_size, void* d_ws, size_t ws_size,
                              hipStream_t stream) {
    const float* x  = (const float*)d_in[0];
    const float* Wq = (const float*)d_in[1];
    const float* Wk = (const float*)d_in[2];
    const float* Wv = (const float*)d_in[3];
    const float* Wo = (const float*)d_in[4];
    float* out = (float*)d_out;

    char* ws = (char*)d_ws;
    unsigned short* xthi = (unsigned short*)(ws + XTH_OFF);
    unsigned short* xtlo = (unsigned short*)(ws + XTL_OFF);
    unsigned short* ht   = (unsigned short*)(ws + HT_OFF);

    prep     <<<192,     256,  0, stream>>>(x, xthi, xtlo);
    qkv_attn <<<HB,      1024, 0, stream>>>(xthi, xtlo, Wq, Wk, Wv, ht);
    out_mfma <<<NB * 32, 256,  0, stream>>>(Wo, ht, out);
}

// Round 5
// 113.221 us; speedup vs baseline: 1.1477x; 1.0330x over previous
//
#include <hip/hip_runtime.h>
#include <math.h>

#define NB 24
#define DM 128
#define NH 8
#define DK 16
#define LL 512
#define HB (NH * NB)   // 192

// ---------------------------------------------------------------------------
// Workspace layout (BYTES):
//   xThi/xTlo [NB][LL][DM] ushort : x transposed, split bf16 (B-frag layout)
//   headT     [NB][LL][DM]        : attention out, bf16, B-frag layout for Wo
// (W split is done in-kernel from fp32; qb/kb/vb live in LDS.)
// ---------------------------------------------------------------------------
#define XTH_OFF 0
#define XTL_OFF 3145728
#define HT_OFF  6291456

typedef __attribute__((ext_vector_type(8))) short bf16x8;   // 4 VGPR MFMA A/B
typedef __attribute__((ext_vector_type(4))) float f32x4;    // MFMA C/D
typedef __attribute__((ext_vector_type(4))) int   i32x4;

#define MFMA  __builtin_amdgcn_mfma_f32_16x16x32_bf16
#define EXP2  __builtin_amdgcn_exp2f
#define BPERM __builtin_amdgcn_ds_bpermute

// bf16 rounding (round-half-up), result kept in the high half of a uint
static __device__ __forceinline__ unsigned bfr(float x) {
    return (__float_as_uint(x) + 0x8000u) & 0xffff0000u;
}

// packed bf16 pair via HW cvt: lo16 = bf16(a), hi16 = bf16(b)  (RNE)
static __device__ __forceinline__ unsigned cvtpk(float a, float b) {
    unsigned r;
    asm("v_cvt_pk_bf16_f32 %0, %1, %2" : "=v"(r) : "v"(a), "v"(b));
    return r;
}

// split 8 consecutive fp32 into hi/lo bf16x8 A-fragments (same bfr math as
// the original prep W-split: bit-identical results)
static __device__ __forceinline__ void wsplit(const float* __restrict__ p,
                                              bf16x8& aH, bf16x8& aL) {
    const float4 f0 = *(const float4*)p;
    const float4 f1 = *(const float4*)(p + 4);
    const float f[8] = {f0.x, f0.y, f0.z, f0.w, f1.x, f1.y, f1.z, f1.w};
    i32x4 h, l;
    #pragma unroll
    for (int q = 0; q < 4; ++q) {
        const unsigned h0 = bfr(f[2 * q]), h1 = bfr(f[2 * q + 1]);
        const unsigned e0 = bfr(f[2 * q]     - __uint_as_float(h0));
        const unsigned e1 = bfr(f[2 * q + 1] - __uint_as_float(h1));
        h[q] = (int)((h0 >> 16) | (h1 & 0xffff0000u));
        l[q] = (int)((e0 >> 16) | (e1 & 0xffff0000u));
    }
    aH = __builtin_bit_cast(bf16x8, h);
    aL = __builtin_bit_cast(bf16x8, l);
}

// ---------------------------------------------------------------------------
// Kernel 0: prep. 192 blocks: x -> xThi/xTlo (LDS transpose, two 64-row
// halves, 16.6 KB LDS).
// ---------------------------------------------------------------------------
__global__ __launch_bounds__(256)
void prep(const float* __restrict__ x,
          unsigned short* __restrict__ xthi,
          unsigned short* __restrict__ xtlo)
{
    __shared__ float T[64][65];                       // 16.6 KB
    const int bid = blockIdx.x, tid = threadIdx.x;
    const int b = bid >> 3, lc = bid & 7;

    #pragma unroll
    for (int half = 0; half < 2; ++half) {
        const int d0 = half << 6;
        const float* __restrict__ xb =
            x + (size_t)b * 65536 + (size_t)d0 * LL + lc * 64;
        if (half) __syncthreads();                    // T reuse fence
        #pragma unroll
        for (int i = 0; i < 16; ++i) {                // coalesced 64-float runs
            const int idx = i * 256 + tid;
            T[idx >> 6][idx & 63] = xb[(size_t)(idx >> 6) * LL + (idx & 63)];
        }
        __syncthreads();
        #pragma unroll
        for (int i = 0; i < 8; ++i) {                 // 2 elems/lane, packed
            const int idx = (i * 256 + tid) * 2;
            const int l = idx >> 6, dd = idx & 63;
            const float v0 = T[dd][l], v1 = T[dd + 1][l];
            const unsigned h0 = bfr(v0), h1 = bfr(v1);
            const unsigned e0 = bfr(v0 - __uint_as_float(h0));
            const unsigned e1 = bfr(v1 - __uint_as_float(h1));
            const size_t o = (size_t)b * 65536 +
                             (size_t)(lc * 64 + l) * DM + d0 + dd;
            *(unsigned*)(xthi + o) = (h0 >> 16) | (h1 & 0xffff0000u);
            *(unsigned*)(xtlo + o) = (e0 >> 16) | (e1 & 0xffff0000u);
        }
    }
}

// ---------------------------------------------------------------------------
// soft_pv with the 4-bperm redistribution (was 8 bperms, half discarded).
// Derivation (validated against the original select table):
//   original: bi[0]=up?B(aLo,c0):B(aLo,c2); bi[1]=up?B(aLo,c1):B(aLo,c3);
//             bi[2]=up?B(aHi,c0):B(aHi,c2); bi[3]=up?B(aHi,c1):B(aHi,c3)
//   aLo only addresses even 16-lane groups, aHi odd groups. Give each SOURCE
//   lane a round word: r0=odd16?c2:c0, r1=odd16?c0:c2, r2=odd16?c3:c1,
//   r3=odd16?c1:c3, and each TARGET a role address: addr0=up?aLo:aHi,
//   addr1=up?aHi:aLo. Then w0=B(addr0,r0), w1=B(addr1,r1), w2=B(addr0,r2),
//   w3=B(addr1,r3) carry all 256 needed words:
//     up:   bi = {w0, w2, w1, w3};   down: bi = {w1, w3, w0, w2}
//   (checked element-wise for g=0,1,2,3.)
// ---------------------------------------------------------------------------
static __device__ __forceinline__ void soft_pv(
    const f32x4& s0, const f32x4& s1, float tm, float& bar, float& sm,
    f32x4& O, const bf16x8& aV, int addr0, int addr1, bool up, bool odd16)
{
    const float nb = fmaxf(bar, tm + 32.f);
    const float f  = EXP2(bar - nb);
    bar = nb;
    const float e0 = EXP2(s0[0] - nb), e1 = EXP2(s0[1] - nb);
    const float e2 = EXP2(s0[2] - nb), e3 = EXP2(s0[3] - nb);
    const float e4 = EXP2(s1[0] - nb), e5 = EXP2(s1[1] - nb);
    const float e6 = EXP2(s1[2] - nb), e7 = EXP2(s1[3] - nb);
    const float sacc = ((e0 + e1) + (e2 + e3)) + ((e4 + e5) + (e6 + e7));
    sm = fmaf(sm, f, sacc);
    O *= f;
    const unsigned c0 = cvtpk(e0, e1), c1 = cvtpk(e2, e3);
    const unsigned c2 = cvtpk(e4, e5), c3 = cvtpk(e6, e7);
    const int r0 = (int)(odd16 ? c2 : c0);
    const int r1 = (int)(odd16 ? c0 : c2);
    const int r2 = (int)(odd16 ? c3 : c1);
    const int r3 = (int)(odd16 ? c1 : c3);
    const int w0 = BPERM(addr0, r0);
    const int w1 = BPERM(addr1, r1);
    const int w2 = BPERM(addr0, r2);
    const int w3 = BPERM(addr1, r3);
    i32x4 bi = { up ? w0 : w1, up ? w2 : w3,
                 up ? w1 : w0, up ? w3 : w2 };
    O = MFMA(aV, __builtin_bit_cast(bf16x8, bi), O, 0, 0, 0);
}

#define QK_STRIDE 40     // ushorts per row (32 data + 8 pad)
#define V_STRIDE  520    // ushorts per row (512 data + 8 pad)

// ---------------------------------------------------------------------------
// Fused QKV + attention. 192 blocks (one per hb) x 512 threads (8 waves) --
// the round-2 structure (best measured: VGPR-rich), with in-kernel W split.
// Phase 1: wave wv computes Q/K/V for l in [wv*64, wv*64+64); Q/K/V share
//   the same x B-fragments. Validated LDS layouts (padded strides 40/520).
// Phase 2: wave wv attends for m in [wv*64, +64) as 2 sub-tiles, with the
//   4-bperm soft_pv (LDS-pipe pressure halved).
// ---------------------------------------------------------------------------
__global__ __launch_bounds__(512)
void qkv_attn(const unsigned short* __restrict__ xthi,
              const unsigned short* __restrict__ xtlo,
              const float* __restrict__ Wq,
              const float* __restrict__ Wk,
              const float* __restrict__ Wv,
              unsigned short* __restrict__ ht)
{
    __shared__ unsigned short qs[LL * QK_STRIDE];     // 40 KB
    __shared__ unsigned short ks[LL * QK_STRIDE];     // 40 KB
    __shared__ unsigned short vs[DK * V_STRIDE];      // 16.25 KB

    const int hb    = blockIdx.x;
    const int b     = hb % NB;
    const int wv    = threadIdx.x >> 6;               // 0..7
    const int lane  = threadIdx.x & 63;
    const int g     = lane >> 4;
    const int mR    = lane & 15;
    const int lQ    = wv * 64;

    // ---------------- Phase 1: QKV projection into LDS ----------------
    {
        const float* __restrict__ wqp = Wq + (size_t)hb * 2048 + mR * 128 + g * 8;
        const float* __restrict__ wkp = Wk + (size_t)hb * 2048 + mR * 128 + g * 8;
        const float* __restrict__ wvp = Wv + (size_t)hb * 2048 + mR * 128 + g * 8;
        const unsigned short* __restrict__ xh = xthi + (size_t)b * 65536 + g * 8;
        const unsigned short* __restrict__ xl = xtlo + (size_t)b * 65536 + g * 8;

        f32x4 CQ[4], CK[4], CV[4];
        #pragma unroll
        for (int t = 0; t < 4; ++t) {
            CQ[t] = (f32x4){0.f, 0.f, 0.f, 0.f};
            CK[t] = (f32x4){0.f, 0.f, 0.f, 0.f};
            CV[t] = (f32x4){0.f, 0.f, 0.f, 0.f};
        }

        #pragma unroll
        for (int kk = 0; kk < 4; ++kk) {
            bf16x8 bH[4], bL[4];
            #pragma unroll
            for (int t = 0; t < 4; ++t) {
                const size_t ro = (size_t)(lQ + t * 16 + mR) * DM + kk * 32;
                bH[t] = *(const bf16x8*)(xh + ro);
                bL[t] = *(const bf16x8*)(xl + ro);
            }
            bf16x8 aH, aL;
            wsplit(wqp + kk * 32, aH, aL);
            #pragma unroll
            for (int t = 0; t < 4; ++t) {
                CQ[t] = MFMA(aH, bH[t], CQ[t], 0, 0, 0);
                CQ[t] = MFMA(aH, bL[t], CQ[t], 0, 0, 0);
                CQ[t] = MFMA(aL, bH[t], CQ[t], 0, 0, 0);
            }
            wsplit(wkp + kk * 32, aH, aL);
            #pragma unroll
            for (int t = 0; t < 4; ++t) {
                CK[t] = MFMA(aH, bH[t], CK[t], 0, 0, 0);
                CK[t] = MFMA(aH, bL[t], CK[t], 0, 0, 0);
                CK[t] = MFMA(aL, bH[t], CK[t], 0, 0, 0);
            }
            wsplit(wvp + kk * 32, aH, aL);
            #pragma unroll
            for (int t = 0; t < 4; ++t) {
                CV[t] = MFMA(aH, bH[t], CV[t], 0, 0, 0);
                CV[t] = MFMA(aH, bL[t], CV[t], 0, 0, 0);
                CV[t] = MFMA(aL, bH[t], CV[t], 0, 0, 0);
            }
        }

        // V -> vs[v][l] (plain bf16, padded stride)
        #pragma unroll
        for (int t = 0; t < 4; ++t) {
            const int l = lQ + t * 16 + mR;
            #pragma unroll
            for (int i = 0; i < 4; ++i)
                vs[(4 * g + i) * V_STRIDE + l] =
                    (unsigned short)(bfr(CV[t][i]) >> 16);
        }
        // Q -> split rows [hi(16)|lo(16)], padded stride
        #pragma unroll
        for (int t = 0; t < 4; ++t) {
            const int l = lQ + t * 16 + mR;
            ushort4 hi4, lo4;
            #pragma unroll
            for (int i = 0; i < 4; ++i) {
                const float v = CQ[t][i];
                const unsigned h = bfr(v);
                const unsigned lw = bfr(v - __uint_as_float(h));
                ((unsigned short*)&hi4)[i] = (unsigned short)(h >> 16);
                ((unsigned short*)&lo4)[i] = (unsigned short)(lw >> 16);
            }
            *(ushort4*)(qs + l * QK_STRIDE + 4 * g)      = hi4;
            *(ushort4*)(qs + l * QK_STRIDE + 16 + 4 * g) = lo4;
        }
        // K -> split rows, pre-scaled by 0.25*log2e
        #pragma unroll
        for (int t = 0; t < 4; ++t) {
            const int r = lQ + t * 16 + mR;
            ushort4 hi4, lo4;
            #pragma unroll
            for (int i = 0; i < 4; ++i) {
                const float v = CK[t][i] * (0.25f * 1.44269504f);
                const unsigned h = bfr(v);
                const unsigned lw = bfr(v - __uint_as_float(h));
                ((unsigned short*)&hi4)[i] = (unsigned short)(h >> 16);
                ((unsigned short*)&lo4)[i] = (unsigned short)(lw >> 16);
            }
            *(ushort4*)(ks + r * QK_STRIDE + 4 * g)      = hi4;
            *(ushort4*)(ks + r * QK_STRIDE + 16 + 4 * g) = lo4;
        }
    }

    __syncthreads();

    // ---------------- Phase 2: flash attention from LDS ----------------
    bf16x8 K0[2], K0s[2], K1[2], K1s[2];
    #pragma unroll
    for (int sub = 0; sub < 2; ++sub) {
        const unsigned short* Kr0 = ks + (lQ + sub * 32 + mR) * QK_STRIDE;
        const unsigned short* Kr1 = Kr0 + 16 * QK_STRIDE;
        K0[sub]  = *(const bf16x8*)(Kr0 + g * 8);
        K0s[sub] = *(const bf16x8*)(Kr0 + (g ^ 2) * 8);
        K1[sub]  = *(const bf16x8*)(Kr1 + g * 8);
        K1s[sub] = *(const bf16x8*)(Kr1 + (g ^ 2) * 8);
    }

    const unsigned short* qrow = qs + mR * QK_STRIDE + g * 8;
    const unsigned short* vrow = vs + mR * V_STRIDE + g * 8;

    f32x4 O[2][2];
    float bar[2][2], sm[2][2];
    #pragma unroll
    for (int sub = 0; sub < 2; ++sub)
        #pragma unroll
        for (int gr = 0; gr < 2; ++gr) {
            O[sub][gr]   = (f32x4){0.f, 0.f, 0.f, 0.f};
            bar[sub][gr] = -1e30f;
            sm[sub][gr]  = 0.f;
        }

    const int  aLo   = ((g & 1) * 32 + mR) * 4;
    const int  aHi   = aLo + 64;
    const bool up    = (g < 2);
    const bool odd16 = (g & 1);
    const int  addr0 = up ? aLo : aHi;
    const int  addr1 = up ? aHi : aLo;

    for (int l = 0; l < LL; l += 32) {
        const bf16x8 aQ0 = *(const bf16x8*)(qrow + l * QK_STRIDE);
        const bf16x8 aQ1 = *(const bf16x8*)(qrow + (l + 16) * QK_STRIDE);
        const bf16x8 aV  = *(const bf16x8*)(vrow + l);

        #pragma unroll
        for (int sub = 0; sub < 2; ++sub) {
            const f32x4 z = {0.f,0.f,0.f,0.f};
            f32x4 sA0 = MFMA(aQ0, K0[sub], z, 0,0,0);
            sA0 = MFMA(aQ0, K0s[sub], sA0, 0,0,0);
            f32x4 sB0 = MFMA(aQ0, K1[sub], z, 0,0,0);
            sB0 = MFMA(aQ0, K1s[sub], sB0, 0,0,0);
            f32x4 sA1 = MFMA(aQ1, K0[sub], z, 0,0,0);
            sA1 = MFMA(aQ1, K0s[sub], sA1, 0,0,0);
            f32x4 sB1 = MFMA(aQ1, K1[sub], z, 0,0,0);
            sB1 = MFMA(aQ1, K1s[sub], sB1, 0,0,0);

            float tmA = fmaxf(fmaxf(fmaxf(sA0[0],sA0[1]), fmaxf(sA0[2],sA0[3])),
                              fmaxf(fmaxf(sA1[0],sA1[1]), fmaxf(sA1[2],sA1[3])));
            float tmB = fmaxf(fmaxf(fmaxf(sB0[0],sB0[1]), fmaxf(sB0[2],sB0[3])),
                              fmaxf(fmaxf(sB1[0],sB1[1]), fmaxf(sB1[2],sB1[3])));
            tmA = fmaxf(tmA, __shfl_xor(tmA, 16, 64));
            tmA = fmaxf(tmA, __shfl_xor(tmA, 32, 64));
            tmB = fmaxf(tmB, __shfl_xor(tmB, 16, 64));
            tmB = fmaxf(tmB, __shfl_xor(tmB, 32, 64));

            const bool pA = __any(tmA + 64.f > bar[sub][0]);
            const bool pB = __any(tmB + 64.f > bar[sub][1]);
            if (pA) soft_pv(sA0, sA1, tmA, bar[sub][0], sm[sub][0],
                            O[sub][0], aV, addr0, addr1, up, odd16);
            if (pB) soft_pv(sB0, sB1, tmB, bar[sub][1], sm[sub][1],
                            O[sub][1], aV, addr0, addr1, up, odd16);
        }
    }

    const int h = hb / NB, bb = hb % NB;
    #pragma unroll
    for (int sub = 0; sub < 2; ++sub) {
        float s0 = sm[sub][0], s1 = sm[sub][1];
        s0 += __shfl_xor(s0, 16, 64);  s0 += __shfl_xor(s0, 32, 64);
        s1 += __shfl_xor(s1, 16, 64);  s1 += __shfl_xor(s1, 32, 64);
        const float i0 = 1.f / s0, i1 = 1.f / s1;

        unsigned short* __restrict__ ho =
            ht + (size_t)bb * 65536 +
            (size_t)(lQ + sub * 32 + mR) * DM + h * 16 + 4 * g;
        ushort4 p0, p1;
        #pragma unroll
        for (int i = 0; i < 4; ++i) {
            ((unsigned short*)&p0)[i] =
                (unsigned short)(bfr(O[sub][0][i] * i0) >> 16);
            ((unsigned short*)&p1)[i] =
                (unsigned short)(bfr(O[sub][1][i] * i1) >> 16);
        }
        *(ushort4*)ho             = p0;
        *(ushort4*)(ho + 16 * DM) = p1;
    }
}

// ---------------------------------------------------------------------------
// Kernel 3: out = Wo @ headT on MFMA. 768 blocks = (b, mq 2, nq 16) x 4 waves.
// Wo read as fp32, converted to bf16 A-frags in-kernel.
// ---------------------------------------------------------------------------
__global__ __launch_bounds__(256)
void out_mfma(const float* __restrict__ Wo,
              const unsigned short* __restrict__ ht,
              float* __restrict__ out)
{
    const int blk  = blockIdx.x;
    const int b    = blk >> 5;
    const int mq   = (blk >> 4) & 1;
    const int nq   = blk & 15;
    const int wv   = threadIdx.x >> 6;
    const int lane = threadIdx.x & 63;
    const int g = lane >> 4, mR = lane & 15;
    const int m0 = (mq * 4 + wv) * 16;
    const int n0 = nq * 32;

    const float* __restrict__ A =
        Wo + (size_t)b * 16384 + (size_t)(m0 + mR) * DM + g * 8;
    const unsigned short* __restrict__ B = ht + (size_t)b * 65536 + g * 8;

    f32x4 C0 = {0.f,0.f,0.f,0.f}, C1 = {0.f,0.f,0.f,0.f};
    #pragma unroll
    for (int kk = 0; kk < 4; ++kk) {
        const float4 f0 = *(const float4*)(A + kk * 32);
        const float4 f1 = *(const float4*)(A + kk * 32 + 4);
        i32x4 w;
        w[0] = (int)cvtpk(f0.x, f0.y);
        w[1] = (int)cvtpk(f0.z, f0.w);
        w[2] = (int)cvtpk(f1.x, f1.y);
        w[3] = (int)cvtpk(f1.z, f1.w);
        const bf16x8 aW = __builtin_bit_cast(bf16x8, w);
        const bf16x8 b0 = *(const bf16x8*)(B + (size_t)(n0 + mR) * DM + kk * 32);
        const bf16x8 b1 = *(const bf16x8*)(B + (size_t)(n0 + 16 + mR) * DM + kk * 32);
        C0 = MFMA(aW, b0, C0, 0, 0, 0);
        C1 = MFMA(aW, b1, C1, 0, 0, 0);
    }

    float* __restrict__ ob = out + (size_t)b * 65536 + (size_t)(m0 + 4 * g) * LL;
    #pragma unroll
    for (int i = 0; i < 4; ++i) {
        ob[(size_t)i * LL + n0 + mR]      = C0[i];
        ob[(size_t)i * LL + n0 + 16 + mR] = C1[i];
    }
}

extern "C" void kernel_launch(void* const* d_in, const int* in_sizes, int n_in,
                              void* d_out, int out_size, void* d_ws, size_t ws_size,
                              hipStream_t stream) {
    const float* x  = (const float*)d_in[0];
    const float* Wq = (const float*)d_in[1];
    const float* Wk = (const float*)d_in[2];
    const float* Wv = (const float*)d_in[3];
    const float* Wo = (const float*)d_in[4];
    float* out = (float*)d_out;

    char* ws = (char*)d_ws;
    unsigned short* xthi = (unsigned short*)(ws + XTH_OFF);
    unsigned short* xtlo = (unsigned short*)(ws + XTL_OFF);
    unsigned short* ht   = (unsigned short*)(ws + HT_OFF);

    prep     <<<192,     256, 0, stream>>>(x, xthi, xtlo);
    qkv_attn <<<HB,      512, 0, stream>>>(xthi, xtlo, Wq, Wk, Wv, ht);
    out_mfma <<<NB * 32, 256, 0, stream>>>(Wo, ht, out);
}

// Round 6
// 112.645 us; speedup vs baseline: 1.1536x; 1.0051x over previous
//
#include <hip/hip_runtime.h>
#include <math.h>

#define NB 24
#define DM 128
#define NH 8
#define DK 16
#define LL 512
#define HB (NH * NB)   // 192

// ---------------------------------------------------------------------------
// Workspace layout (BYTES):
//   xThi/xTlo [NB][LL][DM] ushort : x transposed, split bf16 (B-frag layout)
//   headT     [NB][LL][DM]        : attention out, bf16, B-frag layout for Wo
// (W split is done in-kernel from fp32; qb/kb/vb live in LDS.)
// ---------------------------------------------------------------------------
#define XTH_OFF 0
#define XTL_OFF 3145728
#define HT_OFF  6291456

typedef __attribute__((ext_vector_type(8))) short bf16x8;   // 4 VGPR MFMA A/B
typedef __attribute__((ext_vector_type(4))) float f32x4;    // MFMA C/D
typedef __attribute__((ext_vector_type(4))) int   i32x4;

#define MFMA  __builtin_amdgcn_mfma_f32_16x16x32_bf16
#define EXP2  __builtin_amdgcn_exp2f
#define BPERM __builtin_amdgcn_ds_bpermute

// bf16 rounding (round-half-up), result kept in the high half of a uint
static __device__ __forceinline__ unsigned bfr(float x) {
    return (__float_as_uint(x) + 0x8000u) & 0xffff0000u;
}

// packed bf16 pair via HW cvt: lo16 = bf16(a), hi16 = bf16(b)  (RNE)
static __device__ __forceinline__ unsigned cvtpk(float a, float b) {
    unsigned r;
    asm("v_cvt_pk_bf16_f32 %0, %1, %2" : "=v"(r) : "v"(a), "v"(b));
    return r;
}

// split 8 consecutive fp32 into hi/lo bf16x8 A-fragments
static __device__ __forceinline__ void wsplit(const float* __restrict__ p,
                                              bf16x8& aH, bf16x8& aL) {
    const float4 f0 = *(const float4*)p;
    const float4 f1 = *(const float4*)(p + 4);
    const float f[8] = {f0.x, f0.y, f0.z, f0.w, f1.x, f1.y, f1.z, f1.w};
    i32x4 h, l;
    #pragma unroll
    for (int q = 0; q < 4; ++q) {
        const unsigned h0 = bfr(f[2 * q]), h1 = bfr(f[2 * q + 1]);
        const unsigned e0 = bfr(f[2 * q]     - __uint_as_float(h0));
        const unsigned e1 = bfr(f[2 * q + 1] - __uint_as_float(h1));
        h[q] = (int)((h0 >> 16) | (h1 & 0xffff0000u));
        l[q] = (int)((e0 >> 16) | (e1 & 0xffff0000u));
    }
    aH = __builtin_bit_cast(bf16x8, h);
    aL = __builtin_bit_cast(bf16x8, l);
}

// ---------------------------------------------------------------------------
// Kernel 0: prep. 192 blocks: x -> xThi/xTlo (LDS transpose, two 64-row
// halves, 16.6 KB LDS).
// ---------------------------------------------------------------------------
__global__ __launch_bounds__(256)
void prep(const float* __restrict__ x,
          unsigned short* __restrict__ xthi,
          unsigned short* __restrict__ xtlo)
{
    __shared__ float T[64][65];                       // 16.6 KB
    const int bid = blockIdx.x, tid = threadIdx.x;
    const int b = bid >> 3, lc = bid & 7;

    #pragma unroll
    for (int half = 0; half < 2; ++half) {
        const int d0 = half << 6;
        const float* __restrict__ xb =
            x + (size_t)b * 65536 + (size_t)d0 * LL + lc * 64;
        if (half) __syncthreads();                    // T reuse fence
        #pragma unroll
        for (int i = 0; i < 16; ++i) {                // coalesced 64-float runs
            const int idx = i * 256 + tid;
            T[idx >> 6][idx & 63] = xb[(size_t)(idx >> 6) * LL + (idx & 63)];
        }
        __syncthreads();
        #pragma unroll
        for (int i = 0; i < 8; ++i) {                 // 2 elems/lane, packed
            const int idx = (i * 256 + tid) * 2;
            const int l = idx >> 6, dd = idx & 63;
            const float v0 = T[dd][l], v1 = T[dd + 1][l];
            const unsigned h0 = bfr(v0), h1 = bfr(v1);
            const unsigned e0 = bfr(v0 - __uint_as_float(h0));
            const unsigned e1 = bfr(v1 - __uint_as_float(h1));
            const size_t o = (size_t)b * 65536 +
                             (size_t)(lc * 64 + l) * DM + d0 + dd;
            *(unsigned*)(xthi + o) = (h0 >> 16) | (h1 & 0xffff0000u);
            *(unsigned*)(xtlo + o) = (e0 >> 16) | (e1 & 0xffff0000u);
        }
    }
}

// ---------------------------------------------------------------------------
// pv_acc: branch-free exp + P-redistribution + PV accumulate. M is a
// loop-invariant per-column shift (softmax is invariant to it). The 4-bperm
// redistribution is the r5-validated mapping:
//   up:   bi = {w0, w2, w1, w3};   down: bi = {w1, w3, w0, w2}
//   w0=B(addr0, odd16?c2:c0)  w1=B(addr1, odd16?c0:c2)
//   w2=B(addr0, odd16?c3:c1)  w3=B(addr1, odd16?c1:c3)
// ---------------------------------------------------------------------------
static __device__ __forceinline__ void pv_acc(
    const f32x4& s0, const f32x4& s1, float M, float& sm,
    f32x4& O, const bf16x8& aV, int addr0, int addr1, bool up, bool odd16)
{
    const float e0 = EXP2(s0[0] - M), e1 = EXP2(s0[1] - M);
    const float e2 = EXP2(s0[2] - M), e3 = EXP2(s0[3] - M);
    const float e4 = EXP2(s1[0] - M), e5 = EXP2(s1[1] - M);
    const float e6 = EXP2(s1[2] - M), e7 = EXP2(s1[3] - M);
    sm += ((e0 + e1) + (e2 + e3)) + ((e4 + e5) + (e6 + e7));
    const unsigned c0 = cvtpk(e0, e1), c1 = cvtpk(e2, e3);
    const unsigned c2 = cvtpk(e4, e5), c3 = cvtpk(e6, e7);
    const int r0 = (int)(odd16 ? c2 : c0);
    const int r1 = (int)(odd16 ? c0 : c2);
    const int r2 = (int)(odd16 ? c3 : c1);
    const int r3 = (int)(odd16 ? c1 : c3);
    const int w0 = BPERM(addr0, r0);
    const int w1 = BPERM(addr1, r1);
    const int w2 = BPERM(addr0, r2);
    const int w3 = BPERM(addr1, r3);
    i32x4 bi = { up ? w0 : w1, up ? w2 : w3,
                 up ? w1 : w0, up ? w3 : w2 };
    O = MFMA(aV, __builtin_bit_cast(bf16x8, bi), O, 0, 0, 0);
}

#define QK_STRIDE 40     // ushorts per row (32 data + 8 pad)
#define V_STRIDE  520    // ushorts per row (512 data + 8 pad)

// ---------------------------------------------------------------------------
// Fused QKV + attention. 192 blocks (one per hb) x 512 threads (8 waves).
// Phase 1: wave wv computes Q/K/V for l in [wv*64, wv*64+64); validated LDS
//   layouts (padded strides 40/520).
// Phase 2 is now TWO-PASS (replaces online softmax -- removes the serial
//   per-step bar/sm/O chain that pinned dur at ~42us across r2-r5):
//   pass 1: approximate per-column max via 1 MFMA/tile (hi.hi+lo.lo only;
//     cross-term error ~2 log2 units; softmax invariant to the shift, only
//     bounds e <= 2^err -- safe). Steps independent, pipelines fully.
//   pass 2: full-precision QK, exp2(s - M) with loop-invariant M, 4-bperm
//     redistribution, PV MFMA accumulate. No branches, no shfls, no rescale.
// ---------------------------------------------------------------------------
__global__ __launch_bounds__(512)
void qkv_attn(const unsigned short* __restrict__ xthi,
              const unsigned short* __restrict__ xtlo,
              const float* __restrict__ Wq,
              const float* __restrict__ Wk,
              const float* __restrict__ Wv,
              unsigned short* __restrict__ ht)
{
    __shared__ unsigned short qs[LL * QK_STRIDE];     // 40 KB
    __shared__ unsigned short ks[LL * QK_STRIDE];     // 40 KB
    __shared__ unsigned short vs[DK * V_STRIDE];      // 16.25 KB

    const int hb    = blockIdx.x;
    const int b     = hb % NB;
    const int wv    = threadIdx.x >> 6;               // 0..7
    const int lane  = threadIdx.x & 63;
    const int g     = lane >> 4;
    const int mR    = lane & 15;
    const int lQ    = wv * 64;

    // ---------------- Phase 1: QKV projection into LDS ----------------
    {
        const float* __restrict__ wqp = Wq + (size_t)hb * 2048 + mR * 128 + g * 8;
        const float* __restrict__ wkp = Wk + (size_t)hb * 2048 + mR * 128 + g * 8;
        const float* __restrict__ wvp = Wv + (size_t)hb * 2048 + mR * 128 + g * 8;
        const unsigned short* __restrict__ xh = xthi + (size_t)b * 65536 + g * 8;
        const unsigned short* __restrict__ xl = xtlo + (size_t)b * 65536 + g * 8;

        f32x4 CQ[4], CK[4], CV[4];
        #pragma unroll
        for (int t = 0; t < 4; ++t) {
            CQ[t] = (f32x4){0.f, 0.f, 0.f, 0.f};
            CK[t] = (f32x4){0.f, 0.f, 0.f, 0.f};
            CV[t] = (f32x4){0.f, 0.f, 0.f, 0.f};
        }

        #pragma unroll
        for (int kk = 0; kk < 4; ++kk) {
            bf16x8 bH[4], bL[4];
            #pragma unroll
            for (int t = 0; t < 4; ++t) {
                const size_t ro = (size_t)(lQ + t * 16 + mR) * DM + kk * 32;
                bH[t] = *(const bf16x8*)(xh + ro);
                bL[t] = *(const bf16x8*)(xl + ro);
            }
            bf16x8 aH, aL;
            wsplit(wqp + kk * 32, aH, aL);
            #pragma unroll
            for (int t = 0; t < 4; ++t) {
                CQ[t] = MFMA(aH, bH[t], CQ[t], 0, 0, 0);
                CQ[t] = MFMA(aH, bL[t], CQ[t], 0, 0, 0);
                CQ[t] = MFMA(aL, bH[t], CQ[t], 0, 0, 0);
            }
            wsplit(wkp + kk * 32, aH, aL);
            #pragma unroll
            for (int t = 0; t < 4; ++t) {
                CK[t] = MFMA(aH, bH[t], CK[t], 0, 0, 0);
                CK[t] = MFMA(aH, bL[t], CK[t], 0, 0, 0);
                CK[t] = MFMA(aL, bH[t], CK[t], 0, 0, 0);
            }
            wsplit(wvp + kk * 32, aH, aL);
            #pragma unroll
            for (int t = 0; t < 4; ++t) {
                CV[t] = MFMA(aH, bH[t], CV[t], 0, 0, 0);
                CV[t] = MFMA(aH, bL[t], CV[t], 0, 0, 0);
                CV[t] = MFMA(aL, bH[t], CV[t], 0, 0, 0);
            }
        }

        // V -> vs[v][l] (plain bf16, padded stride)
        #pragma unroll
        for (int t = 0; t < 4; ++t) {
            const int l = lQ + t * 16 + mR;
            #pragma unroll
            for (int i = 0; i < 4; ++i)
                vs[(4 * g + i) * V_STRIDE + l] =
                    (unsigned short)(bfr(CV[t][i]) >> 16);
        }
        // Q -> split rows [hi(16)|lo(16)], padded stride
        #pragma unroll
        for (int t = 0; t < 4; ++t) {
            const int l = lQ + t * 16 + mR;
            ushort4 hi4, lo4;
            #pragma unroll
            for (int i = 0; i < 4; ++i) {
                const float v = CQ[t][i];
                const unsigned h = bfr(v);
                const unsigned lw = bfr(v - __uint_as_float(h));
                ((unsigned short*)&hi4)[i] = (unsigned short)(h >> 16);
                ((unsigned short*)&lo4)[i] = (unsigned short)(lw >> 16);
            }
            *(ushort4*)(qs + l * QK_STRIDE + 4 * g)      = hi4;
            *(ushort4*)(qs + l * QK_STRIDE + 16 + 4 * g) = lo4;
        }
        // K -> split rows, pre-scaled by 0.25*log2e
        #pragma unroll
        for (int t = 0; t < 4; ++t) {
            const int r = lQ + t * 16 + mR;
            ushort4 hi4, lo4;
            #pragma unroll
            for (int i = 0; i < 4; ++i) {
                const float v = CK[t][i] * (0.25f * 1.44269504f);
                const unsigned h = bfr(v);
                const unsigned lw = bfr(v - __uint_as_float(h));
                ((unsigned short*)&hi4)[i] = (unsigned short)(h >> 16);
                ((unsigned short*)&lo4)[i] = (unsigned short)(lw >> 16);
            }
            *(ushort4*)(ks + r * QK_STRIDE + 4 * g)      = hi4;
            *(ushort4*)(ks + r * QK_STRIDE + 16 + 4 * g) = lo4;
        }
    }

    __syncthreads();

    // ---------------- Phase 2: two-pass softmax attention ----------------
    bf16x8 K0[2], K0s[2], K1[2], K1s[2];
    #pragma unroll
    for (int sub = 0; sub < 2; ++sub) {
        const unsigned short* Kr0 = ks + (lQ + sub * 32 + mR) * QK_STRIDE;
        const unsigned short* Kr1 = Kr0 + 16 * QK_STRIDE;
        K0[sub]  = *(const bf16x8*)(Kr0 + g * 8);
        K0s[sub] = *(const bf16x8*)(Kr0 + (g ^ 2) * 8);
        K1[sub]  = *(const bf16x8*)(Kr1 + g * 8);
        K1s[sub] = *(const bf16x8*)(Kr1 + (g ^ 2) * 8);
    }

    const unsigned short* qrow = qs + mR * QK_STRIDE + g * 8;
    const unsigned short* vrow = vs + mR * V_STRIDE + g * 8;

    const int  aLo   = ((g & 1) * 32 + mR) * 4;
    const int  aHi   = aLo + 64;
    const bool up    = (g < 2);
    const bool odd16 = (g & 1);
    const int  addr0 = up ? aLo : aHi;
    const int  addr1 = up ? aHi : aLo;

    // ---- pass 1: approximate per-column maxima (1 MFMA per tile) ----
    float MA[2] = {-1e30f, -1e30f}, MB[2] = {-1e30f, -1e30f};
    for (int l = 0; l < LL; l += 32) {
        const bf16x8 aQ0 = *(const bf16x8*)(qrow + l * QK_STRIDE);
        const bf16x8 aQ1 = *(const bf16x8*)(qrow + (l + 16) * QK_STRIDE);
        #pragma unroll
        for (int sub = 0; sub < 2; ++sub) {
            const f32x4 z = {0.f,0.f,0.f,0.f};
            const f32x4 sA0 = MFMA(aQ0, K0[sub], z, 0,0,0);
            const f32x4 sB0 = MFMA(aQ0, K1[sub], z, 0,0,0);
            const f32x4 sA1 = MFMA(aQ1, K0[sub], z, 0,0,0);
            const f32x4 sB1 = MFMA(aQ1, K1[sub], z, 0,0,0);
            float tmA = fmaxf(fmaxf(fmaxf(sA0[0],sA0[1]), fmaxf(sA0[2],sA0[3])),
                              fmaxf(fmaxf(sA1[0],sA1[1]), fmaxf(sA1[2],sA1[3])));
            float tmB = fmaxf(fmaxf(fmaxf(sB0[0],sB0[1]), fmaxf(sB0[2],sB0[3])),
                              fmaxf(fmaxf(sB1[0],sB1[1]), fmaxf(sB1[2],sB1[3])));
            tmA = fmaxf(tmA, __shfl_xor(tmA, 16, 64));
            tmA = fmaxf(tmA, __shfl_xor(tmA, 32, 64));
            tmB = fmaxf(tmB, __shfl_xor(tmB, 16, 64));
            tmB = fmaxf(tmB, __shfl_xor(tmB, 32, 64));
            MA[sub] = fmaxf(MA[sub], tmA);
            MB[sub] = fmaxf(MB[sub], tmB);
        }
    }

    // ---- pass 2: full QK, exp2(s-M), P redistribution, PV accumulate ----
    f32x4 O[2][2];
    float smA[2] = {0.f, 0.f}, smB[2] = {0.f, 0.f};
    #pragma unroll
    for (int sub = 0; sub < 2; ++sub)
        #pragma unroll
        for (int gr = 0; gr < 2; ++gr)
            O[sub][gr] = (f32x4){0.f, 0.f, 0.f, 0.f};

    for (int l = 0; l < LL; l += 32) {
        const bf16x8 aQ0 = *(const bf16x8*)(qrow + l * QK_STRIDE);
        const bf16x8 aQ1 = *(const bf16x8*)(qrow + (l + 16) * QK_STRIDE);
        const bf16x8 aV  = *(const bf16x8*)(vrow + l);

        #pragma unroll
        for (int sub = 0; sub < 2; ++sub) {
            const f32x4 z = {0.f,0.f,0.f,0.f};
            f32x4 sA0 = MFMA(aQ0, K0[sub], z, 0,0,0);
            sA0 = MFMA(aQ0, K0s[sub], sA0, 0,0,0);
            f32x4 sB0 = MFMA(aQ0, K1[sub], z, 0,0,0);
            sB0 = MFMA(aQ0, K1s[sub], sB0, 0,0,0);
            f32x4 sA1 = MFMA(aQ1, K0[sub], z, 0,0,0);
            sA1 = MFMA(aQ1, K0s[sub], sA1, 0,0,0);
            f32x4 sB1 = MFMA(aQ1, K1[sub], z, 0,0,0);
            sB1 = MFMA(aQ1, K1s[sub], sB1, 0,0,0);

            pv_acc(sA0, sA1, MA[sub], smA[sub], O[sub][0], aV,
                   addr0, addr1, up, odd16);
            pv_acc(sB0, sB1, MB[sub], smB[sub], O[sub][1], aV,
                   addr0, addr1, up, odd16);
        }
    }

    const int h = hb / NB, bb = hb % NB;
    #pragma unroll
    for (int sub = 0; sub < 2; ++sub) {
        float s0 = smA[sub], s1 = smB[sub];
        s0 += __shfl_xor(s0, 16, 64);  s0 += __shfl_xor(s0, 32, 64);
        s1 += __shfl_xor(s1, 16, 64);  s1 += __shfl_xor(s1, 32, 64);
        const float i0 = 1.f / s0, i1 = 1.f / s1;

        unsigned short* __restrict__ ho =
            ht + (size_t)bb * 65536 +
            (size_t)(lQ + sub * 32 + mR) * DM + h * 16 + 4 * g;
        ushort4 p0, p1;
        #pragma unroll
        for (int i = 0; i < 4; ++i) {
            ((unsigned short*)&p0)[i] =
                (unsigned short)(bfr(O[sub][0][i] * i0) >> 16);
            ((unsigned short*)&p1)[i] =
                (unsigned short)(bfr(O[sub][1][i] * i1) >> 16);
        }
        *(ushort4*)ho             = p0;
        *(ushort4*)(ho + 16 * DM) = p1;
    }
}

// ---------------------------------------------------------------------------
// Kernel 3: out = Wo @ headT on MFMA. 768 blocks = (b, mq 2, nq 16) x 4 waves.
// Wo read as fp32, converted to bf16 A-frags in-kernel.
// ---------------------------------------------------------------------------
__global__ __launch_bounds__(256)
void out_mfma(const float* __restrict__ Wo,
              const unsigned short* __restrict__ ht,
              float* __restrict__ out)
{
    const int blk  = blockIdx.x;
    const int b    = blk >> 5;
    const int mq   = (blk >> 4) & 1;
    const int nq   = blk & 15;
    const int wv   = threadIdx.x >> 6;
    const int lane = threadIdx.x & 63;
    const int g = lane >> 4, mR = lane & 15;
    const int m0 = (mq * 4 + wv) * 16;
    const int n0 = nq * 32;

    const float* __restrict__ A =
        Wo + (size_t)b * 16384 + (size_t)(m0 + mR) * DM + g * 8;
    const unsigned short* __restrict__ B = ht + (size_t)b * 65536 + g * 8;

    f32x4 C0 = {0.f,0.f,0.f,0.f}, C1 = {0.f,0.f,0.f,0.f};
    #pragma unroll
    for (int kk = 0; kk < 4; ++kk) {
        const float4 f0 = *(const float4*)(A + kk * 32);
        const float4 f1 = *(const float4*)(A + kk * 32 + 4);
        i32x4 w;
        w[0] = (int)cvtpk(f0.x, f0.y);
        w[1] = (int)cvtpk(f0.z, f0.w);
        w[2] = (int)cvtpk(f1.x, f1.y);
        w[3] = (int)cvtpk(f1.z, f1.w);
        const bf16x8 aW = __builtin_bit_cast(bf16x8, w);
        const bf16x8 b0 = *(const bf16x8*)(B + (size_t)(n0 + mR) * DM + kk * 32);
        const bf16x8 b1 = *(const bf16x8*)(B + (size_t)(n0 + 16 + mR) * DM + kk * 32);
        C0 = MFMA(aW, b0, C0, 0, 0, 0);
        C1 = MFMA(aW, b1, C1, 0, 0, 0);
    }

    float* __restrict__ ob = out + (size_t)b * 65536 + (size_t)(m0 + 4 * g) * LL;
    #pragma unroll
    for (int i = 0; i < 4; ++i) {
        ob[(size_t)i * LL + n0 + mR]      = C0[i];
        ob[(size_t)i * LL + n0 + 16 + mR] = C1[i];
    }
}

extern "C" void kernel_launch(void* const* d_in, const int* in_sizes, int n_in,
                              void* d_out, int out_size, void* d_ws, size_t ws_size,
                              hipStream_t stream) {
    const float* x  = (const float*)d_in[0];
    const float* Wq = (const float*)d_in[1];
    const float* Wk = (const float*)d_in[2];
    const float* Wv = (const float*)d_in[3];
    const float* Wo = (const float*)d_in[4];
    float* out = (float*)d_out;

    char* ws = (char*)d_ws;
    unsigned short* xthi = (unsigned short*)(ws + XTH_OFF);
    unsigned short* xtlo = (unsigned short*)(ws + XTL_OFF);
    unsigned short* ht   = (unsigned short*)(ws + HT_OFF);

    prep     <<<192,     256, 0, stream>>>(x, xthi, xtlo);
    qkv_attn <<<HB,      512, 0, stream>>>(xthi, xtlo, Wq, Wk, Wv, ht);
    out_mfma <<<NB * 32, 256, 0, stream>>>(Wo, ht, out);
}